// Round 4
// baseline (72.336 us; speedup 1.0000x reference)
//
#include <hip/hip_runtime.h>

typedef unsigned short u16;
typedef short bf16x8 __attribute__((ext_vector_type(8)));
typedef float f32x4 __attribute__((ext_vector_type(4)));

#define AS1 __attribute__((address_space(1)))
#define AS3 __attribute__((address_space(3)))

__device__ __forceinline__ u16 f2bf(float f) {
    unsigned u = __float_as_uint(f);
    u += 0x7fffu + ((u >> 16) & 1u);   // RNE
    return (u16)(u >> 16);
}
__device__ __forceinline__ float bf2f(u16 h) {
    return __uint_as_float(((unsigned)h) << 16);
}

__device__ __forceinline__ void gload_lds16(const void* g, void* l) {
    __builtin_amdgcn_global_load_lds((AS1 unsigned int*)(g),
                                     (AS3 unsigned int*)(l), 16, 0, 0);
}

// ---------------- stage 1: prep (W0/W1 cvt + Qt/E1 build, one launch) ----------------
__global__ void prep_kernel(const float* __restrict__ W0, const float* __restrict__ W1,
                            const float* __restrict__ x, const float* __restrict__ emb,
                            u16* __restrict__ W0b, u16* __restrict__ W1b,
                            u16* __restrict__ Qt, u16* __restrict__ E1) {
    int gid = blockIdx.x;
    if (gid < 4608) {                       // cvt W0 (4096 blocks) + W1 (512 blocks)
        int i = gid * 256 + threadIdx.x;
        const float* src; u16* dst; int j;
        if (i < 1048576) { src = W0; dst = W0b; j = i; }
        else             { src = W1; dst = W1b; j = i - 1048576; }
        float4 v = reinterpret_cast<const float4*>(src)[j];
        ushort4 o;
        o.x = f2bf(v.x); o.y = f2bf(v.y); o.z = f2bf(v.z); o.w = f2bf(v.w);
        reinterpret_cast<ushort4*>(dst)[j] = o;
    } else {                                // build Qt + E1: 1024 blocks x 4 n each
        int n = (gid - 4608) * 4 + (threadIdx.x >> 6);
        int lane = threadIdx.x & 63;
        int b = n >> 4, d = n & 15;
        int m0 = lane * 4;
        float4 xv = *reinterpret_cast<const float4*>(x + b * 256 + m0);
        ushort4 q;
        q.x = f2bf(xv.x * emb[(m0 + 0) * 16 + d]);
        q.y = f2bf(xv.y * emb[(m0 + 1) * 16 + d]);
        q.z = f2bf(xv.z * emb[(m0 + 2) * 16 + d]);
        q.w = f2bf(xv.w * emb[(m0 + 3) * 16 + d]);
        *reinterpret_cast<ushort4*>(Qt + n * 256 + m0) = q;
        int e1 = (n >> 8) * 65536 + (m0 >> 7) * 32768 + ((n >> 6) & 3) * 8192
               + ((m0 >> 4) & 7) * 1024 + ((n >> 4) & 3) * 256
               + ((((m0 >> 2) & 3) << 4) + (n & 15)) * 4;
        *reinterpret_cast<ushort4*>(E1 + e1) = q;
    }
}

// ---------------- stage 2: layer 1 (fused GEMM + h-reduction) ----------------
// 1024 blocks, 512 threads. Tile 256h x 256n, K=256, BK=32, 4 LDS bufs, depth-3
// staging + one-chunk-ahead register preread (LDS pipe overlaps matrix pipe).
__global__ __launch_bounds__(512, 2) void cin1_kernel(
    const u16* __restrict__ W0b, const u16* __restrict__ Qt, const u16* __restrict__ E1,
    const float* __restrict__ b0, u16* __restrict__ E2, float* __restrict__ S1)
{
    __shared__ __attribute__((aligned(16))) u16 As[4][8192];
    __shared__ __attribute__((aligned(16))) u16 Bs[4][8192];
    __shared__ float part[2][256];

    const int tid = threadIdx.x, lane = tid & 63, w = tid >> 6;
    const int wh = w >> 2, wn = w & 3;
    const int lid = blockIdx.x;
    const int g8 = lid & 7, m = lid >> 3;
    const int o = ((g8 >> 1) << 4) | (m & 15);
    const int ntile = ((g8 & 1) << 3) | (m >> 4);

    const int dr = ((lane >> 3) << 1) | (lane & 1);
    const int dk = (((lane & 7) >> 1) ^ ((lane >> 3) & 3)) << 3;
    const u16* aSrc0 = W0b + (o * 256 + (w * 2 + 0) * 16 + dr) * 256 + dk;
    const u16* aSrc1 = W0b + (o * 256 + (w * 2 + 1) * 16 + dr) * 256 + dk;
    const u16* bSrc0 = Qt + (ntile * 256 + (w * 2 + 0) * 16 + dr) * 256 + dk;
    const u16* bSrc1 = Qt + (ntile * 256 + (w * 2 + 1) * 16 + dr) * 256 + dk;
    const int ldsA0 = (w * 2 + 0) * 512, ldsA1 = (w * 2 + 1) * 512;

    const int l2 = (lane & 15) >> 1;
    const int qu = (((((lane >> 4) ^ (l2 & 3)) << 1) | (lane & 1)) << 3);
    const int aOff = wh * 4096 + l2 * 64 + qu;
    const int bOff = wn * 2048 + l2 * 64 + qu;

    f32x4 zero = {0.f, 0.f, 0.f, 0.f};
    f32x4 acc[8][4];
#pragma unroll
    for (int f = 0; f < 8; ++f)
#pragma unroll
        for (int gg = 0; gg < 4; ++gg) acc[f][gg] = zero;

    bf16x8 a[2][8], b[2][4];

    auto stage = [&](int kc, int bb) {
        int ko = kc * 32;
        gload_lds16(aSrc0 + ko, &As[bb][ldsA0]);
        gload_lds16(aSrc1 + ko, &As[bb][ldsA1]);
        gload_lds16(bSrc0 + ko, &Bs[bb][ldsA0]);
        gload_lds16(bSrc1 + ko, &Bs[bb][ldsA1]);
    };

#define PREREAD(kb, pb)                                                              \
    {                                                                                \
        const u16* Ab_ = &As[(kb) & 3][0];                                           \
        const u16* Bb_ = &Bs[(kb) & 3][0];                                           \
        _Pragma("unroll")                                                            \
        for (int f_ = 0; f_ < 8; ++f_)                                               \
            a[pb][f_] = *reinterpret_cast<const bf16x8*>(Ab_ + aOff + f_ * 512);     \
        _Pragma("unroll")                                                            \
        for (int g_ = 0; g_ < 4; ++g_)                                               \
            b[pb][g_] = *reinterpret_cast<const bf16x8*>(Bb_ + bOff + g_ * 512);     \
    }

    stage(0, 0); stage(1, 1); stage(2, 2);
    asm volatile("s_waitcnt vmcnt(8)" ::: "memory");
    __builtin_amdgcn_s_barrier();
    asm volatile("" ::: "memory");
    PREREAD(0, 0);
#pragma unroll
    for (int kc = 0; kc < 8; ++kc) {
        if (kc < 6) asm volatile("s_waitcnt vmcnt(4)" ::: "memory");   // stage(kc+1) visible
        else        asm volatile("s_waitcnt vmcnt(0)" ::: "memory");
        __builtin_amdgcn_s_barrier();
        asm volatile("" ::: "memory");
        const int cur = kc & 1;
        if (kc < 7) PREREAD(kc + 1, cur ^ 1);        // overlaps MFMA cluster below
        __builtin_amdgcn_s_setprio(1);
#pragma unroll
        for (int f = 0; f < 8; ++f)
#pragma unroll
            for (int gg = 0; gg < 4; ++gg)
                acc[f][gg] = __builtin_amdgcn_mfma_f32_16x16x32_bf16(a[cur][f], b[cur][gg], acc[f][gg], 0, 0, 0);
        __builtin_amdgcn_s_setprio(0);
        if (kc < 5) stage(kc + 3, (kc + 3) & 3);
    }
#undef PREREAD

    // epilogue: X1[o][n] = sum_h Q[h][n] * G[h][n], weights pre-packed in E1
    float psum[4] = {0.f, 0.f, 0.f, 0.f};
    const u16* eb = E1 + ntile * 65536 + wh * 32768 + wn * 8192 + lane * 4;
#pragma unroll
    for (int f = 0; f < 8; ++f)
#pragma unroll
        for (int gg = 0; gg < 4; ++gg) {
            ushort4 wv = *reinterpret_cast<const ushort4*>(eb + f * 1024 + gg * 256);
            psum[gg] += bf2f(wv.x) * acc[f][gg][0] + bf2f(wv.y) * acc[f][gg][1]
                      + bf2f(wv.z) * acc[f][gg][2] + bf2f(wv.w) * acc[f][gg][3];
        }
#pragma unroll
    for (int gg = 0; gg < 4; ++gg) {
        float p = psum[gg];
        p += __shfl_xor(p, 16);
        p += __shfl_xor(p, 32);
        if (lane < 16) part[wh][wn * 64 + gg * 16 + lane] = p;
    }
    __syncthreads();
    if (tid < 256) {
        const int nl = tid;
        float v = part[0][nl] + part[1][nl] + b0[o];
        float r = fmaxf(v, 0.0f);
        const int n = ntile * 256 + nl;
        if (o < 32) {
            int idx = ntile * 8192 + (o >> 4) * 4096 + (nl >> 6) * 1024 + ((nl >> 4) & 3) * 256
                    + ((((o >> 2) & 3) << 4) + (nl & 15)) * 4 + (o & 3);
            E2[idx] = f2bf(r);
        } else {
            float s = r;
            s += __shfl_xor(s, 1); s += __shfl_xor(s, 2);
            s += __shfl_xor(s, 4); s += __shfl_xor(s, 8);
            if ((nl & 15) == 0) S1[(n >> 4) * 32 + (o - 32)] = s;
        }
    }
}

// ---------------- stage 3: layer 2 (same schedule) ----------------
__global__ __launch_bounds__(512, 2) void cin2_kernel(
    const u16* __restrict__ W1b, const u16* __restrict__ Qt, const u16* __restrict__ E2,
    const float* __restrict__ b1, float* __restrict__ S2)
{
    __shared__ __attribute__((aligned(16))) u16 As[4][4096];
    __shared__ __attribute__((aligned(16))) u16 Bs[4][8192];
    __shared__ float part[2][2][256];

    const int tid = threadIdx.x, lane = tid & 63, w = tid >> 6;
    const int wh = w >> 2, wn = w & 3;
    const int ntile = blockIdx.x & 15, og = blockIdx.x >> 4;

    const int dr = ((lane >> 3) << 1) | (lane & 1);
    const int dk = (((lane & 7) >> 1) ^ ((lane >> 3) & 3)) << 3;
    const u16* aSrc = W1b + (og * 128 + w * 16 + dr) * 256 + dk;
    const u16* bSrc0 = Qt + (ntile * 256 + (w * 2 + 0) * 16 + dr) * 256 + dk;
    const u16* bSrc1 = Qt + (ntile * 256 + (w * 2 + 1) * 16 + dr) * 256 + dk;
    const int ldsA = w * 512;
    const int ldsB0 = (w * 2 + 0) * 512, ldsB1 = (w * 2 + 1) * 512;

    const int l2 = (lane & 15) >> 1;
    const int qu = (((((lane >> 4) ^ (l2 & 3)) << 1) | (lane & 1)) << 3);
    const int aOff = wh * 2048 + l2 * 64 + qu;
    const int bOff = wn * 2048 + l2 * 64 + qu;

    f32x4 zero = {0.f, 0.f, 0.f, 0.f};
    f32x4 acc[4][4];
#pragma unroll
    for (int f = 0; f < 4; ++f)
#pragma unroll
        for (int gg = 0; gg < 4; ++gg) acc[f][gg] = zero;

    bf16x8 a[2][4], b[2][4];

    auto stage = [&](int kc, int bb) {
        int ko = kc * 32;
        gload_lds16(aSrc + ko, &As[bb][ldsA]);
        gload_lds16(bSrc0 + ko, &Bs[bb][ldsB0]);
        gload_lds16(bSrc1 + ko, &Bs[bb][ldsB1]);
    };

#define PREREAD2(kb, pb)                                                             \
    {                                                                                \
        const u16* Ab_ = &As[(kb) & 3][0];                                           \
        const u16* Bb_ = &Bs[(kb) & 3][0];                                           \
        _Pragma("unroll")                                                            \
        for (int f_ = 0; f_ < 4; ++f_)                                               \
            a[pb][f_] = *reinterpret_cast<const bf16x8*>(Ab_ + aOff + f_ * 512);     \
        _Pragma("unroll")                                                            \
        for (int g_ = 0; g_ < 4; ++g_)                                               \
            b[pb][g_] = *reinterpret_cast<const bf16x8*>(Bb_ + bOff + g_ * 512);     \
    }

    stage(0, 0); stage(1, 1); stage(2, 2);
    asm volatile("s_waitcnt vmcnt(6)" ::: "memory");
    __builtin_amdgcn_s_barrier();
    asm volatile("" ::: "memory");
    PREREAD2(0, 0);
#pragma unroll
    for (int kc = 0; kc < 8; ++kc) {
        if (kc < 6) asm volatile("s_waitcnt vmcnt(3)" ::: "memory");
        else        asm volatile("s_waitcnt vmcnt(0)" ::: "memory");
        __builtin_amdgcn_s_barrier();
        asm volatile("" ::: "memory");
        const int cur = kc & 1;
        if (kc < 7) PREREAD2(kc + 1, cur ^ 1);
        __builtin_amdgcn_s_setprio(1);
#pragma unroll
        for (int f = 0; f < 4; ++f)
#pragma unroll
            for (int gg = 0; gg < 4; ++gg)
                acc[f][gg] = __builtin_amdgcn_mfma_f32_16x16x32_bf16(a[cur][f], b[cur][gg], acc[f][gg], 0, 0, 0);
        __builtin_amdgcn_s_setprio(0);
        if (kc < 5) stage(kc + 3, (kc + 3) & 3);
    }
#undef PREREAD2

    float psum[2][4] = {{0.f,0.f,0.f,0.f},{0.f,0.f,0.f,0.f}};
    const u16* eb = E2 + ntile * 8192 + wn * 1024 + lane * 4;
#pragma unroll
    for (int f = 0; f < 4; ++f)
#pragma unroll
        for (int gg = 0; gg < 4; ++gg) {
            ushort4 wv = *reinterpret_cast<const ushort4*>(eb + (f & 1) * 4096 + gg * 256);
            psum[f >> 1][gg] += bf2f(wv.x) * acc[f][gg][0] + bf2f(wv.y) * acc[f][gg][1]
                              + bf2f(wv.z) * acc[f][gg][2] + bf2f(wv.w) * acc[f][gg][3];
        }
#pragma unroll
    for (int ol = 0; ol < 2; ++ol)
#pragma unroll
        for (int gg = 0; gg < 4; ++gg) {
            float p = psum[ol][gg];
            p += __shfl_xor(p, 16);
            p += __shfl_xor(p, 32);
            if (lane < 16) part[wh][ol][wn * 64 + gg * 16 + lane] = p;
        }
    __syncthreads();
    if (tid < 256) {
        const int nl = tid;
        const int n = ntile * 256 + nl;
#pragma unroll
        for (int ol4 = 0; ol4 < 4; ++ol4) {
            const int oo = og * 4 + ol4;
            float v = part[ol4 >> 1][ol4 & 1][nl] + b1[oo];
            float r = fmaxf(v, 0.0f);
            float s = r;
            s += __shfl_xor(s, 1); s += __shfl_xor(s, 2);
            s += __shfl_xor(s, 4); s += __shfl_xor(s, 8);
            if ((nl & 15) == 0) S2[(n >> 4) * 64 + oo] = s;
        }
    }
}

// ---------------- stage 4: final FC ----------------
__global__ void final_fc_kernel(const float* __restrict__ S1, const float* __restrict__ S2,
                                const float* __restrict__ fcW, const float* __restrict__ fcb,
                                float* __restrict__ out) {
    int b = threadIdx.x;   // 256
    float a0 = fcb[0], a1 = fcb[1];
#pragma unroll 8
    for (int c = 0; c < 32; ++c) {
        float v = S1[b * 32 + c];
        a0 += v * fcW[c]; a1 += v * fcW[96 + c];
    }
#pragma unroll 8
    for (int c = 0; c < 64; ++c) {
        float v = S2[b * 64 + c];
        a0 += v * fcW[32 + c]; a1 += v * fcW[96 + 32 + c];
    }
    out[b * 2 + 0] = a0;
    out[b * 2 + 1] = a1;
}

extern "C" void kernel_launch(void* const* d_in, const int* in_sizes, int n_in,
                              void* d_out, int out_size, void* d_ws, size_t ws_size,
                              hipStream_t stream) {
    const float* x   = (const float*)d_in[0];
    const float* emb = (const float*)d_in[1];
    const float* W0  = (const float*)d_in[2];
    const float* b0  = (const float*)d_in[3];
    const float* W1  = (const float*)d_in[4];
    const float* b1  = (const float*)d_in[5];
    const float* fcW = (const float*)d_in[6];
    const float* fcb = (const float*)d_in[7];
    float* out = (float*)d_out;

    char* ws = (char*)d_ws;
    u16*   W0b = (u16*)(ws);                 //  8,388,608 B
    u16*   W1b = (u16*)(ws + 8388608);       //  1,048,576 B
    u16*   Qt  = (u16*)(ws + 9437184);       //  2,097,152 B
    u16*   E1  = (u16*)(ws + 11534336);      //  2,097,152 B
    u16*   E2  = (u16*)(ws + 13631488);      //    262,144 B
    float* S1  = (float*)(ws + 13893632);    //     32,768 B
    float* S2  = (float*)(ws + 13926400);    //     65,536 B

    prep_kernel<<<5632, 256, 0, stream>>>(W0, W1, x, emb, W0b, W1b, Qt, E1);
    cin1_kernel<<<1024, 512, 0, stream>>>(W0b, Qt, E1, b0, E2, S1);
    cin2_kernel<<<256, 512, 0, stream>>>(W1b, Qt, E2, b1, S2);
    final_fc_kernel<<<1, 256, 0, stream>>>(S1, S2, fcW, fcb, out);
}

// Round 5
// 71.639 us; speedup vs baseline: 1.0097x; 1.0097x over previous
//
#include <hip/hip_runtime.h>

typedef unsigned short u16;
typedef short bf16x8 __attribute__((ext_vector_type(8)));
typedef float f32x4 __attribute__((ext_vector_type(4)));

#define AS1 __attribute__((address_space(1)))
#define AS3 __attribute__((address_space(3)))

__device__ __forceinline__ u16 f2bf(float f) {
    unsigned u = __float_as_uint(f);
    u += 0x7fffu + ((u >> 16) & 1u);   // RNE
    return (u16)(u >> 16);
}
__device__ __forceinline__ float bf2f(u16 h) {
    return __uint_as_float(((unsigned)h) << 16);
}

__device__ __forceinline__ void gload_lds16(const void* g, void* l) {
    __builtin_amdgcn_global_load_lds((AS1 unsigned int*)(g),
                                     (AS3 unsigned int*)(l), 16, 0, 0);
}

// ---------------- stage 1: prep (W0/W1 cvt + Qt/E1 build) ----------------
__global__ void prep_kernel(const float* __restrict__ W0, const float* __restrict__ W1,
                            const float* __restrict__ x, const float* __restrict__ emb,
                            u16* __restrict__ W0b, u16* __restrict__ W1b,
                            u16* __restrict__ Qt, u16* __restrict__ E1) {
    int gid = blockIdx.x;
    if (gid < 4608) {                       // cvt W0 (4096 blocks) + W1 (512 blocks)
        int i = gid * 256 + threadIdx.x;
        const float* src; u16* dst; int j;
        if (i < 1048576) { src = W0; dst = W0b; j = i; }
        else             { src = W1; dst = W1b; j = i - 1048576; }
        float4 v = reinterpret_cast<const float4*>(src)[j];
        ushort4 o;
        o.x = f2bf(v.x); o.y = f2bf(v.y); o.z = f2bf(v.z); o.w = f2bf(v.w);
        reinterpret_cast<ushort4*>(dst)[j] = o;
    } else {                                // build Qt + E1: 1024 blocks x 4 n each
        int n = (gid - 4608) * 4 + (threadIdx.x >> 6);
        int lane = threadIdx.x & 63;
        int b = n >> 4, d = n & 15;
        int m0 = lane * 4;
        float4 xv = *reinterpret_cast<const float4*>(x + b * 256 + m0);
        ushort4 q;
        q.x = f2bf(xv.x * emb[(m0 + 0) * 16 + d]);
        q.y = f2bf(xv.y * emb[(m0 + 1) * 16 + d]);
        q.z = f2bf(xv.z * emb[(m0 + 2) * 16 + d]);
        q.w = f2bf(xv.w * emb[(m0 + 3) * 16 + d]);
        *reinterpret_cast<ushort4*>(Qt + n * 256 + m0) = q;
        // E1 pack: [ntile 32][wh 4][wn 2][f 4][g 4][lane 64][e 4]
        // h=m0..m0+3: wh=h>>6, f=(h>>4)&3, s=(h>>2)&3, e=h&3; n: wn=(n>>6)&1, g=(n>>4)&3, c=n&15
        int e1 = (n >> 7) * 32768 + (m0 >> 6) * 8192 + ((n >> 6) & 1) * 4096
               + ((m0 >> 4) & 3) * 1024 + ((n >> 4) & 3) * 256
               + (((m0 >> 2) & 3) * 16 + (n & 15)) * 4;
        *reinterpret_cast<ushort4*>(E1 + e1) = q;
    }
}

// ---------------- stage 2: layer 1 ----------------
// 2048 blocks x 512 thr. Tile 256h x 128n, BK=32, 3 LDS bufs, depth-2 counted vmcnt.
// 8 waves of 64x64 (wh 0..3, wn 0..1). 2 blocks/CU resident.
__global__ __launch_bounds__(512, 4) void cin1_kernel(
    const u16* __restrict__ W0b, const u16* __restrict__ Qt, const u16* __restrict__ E1,
    const float* __restrict__ b0, u16* __restrict__ E2, float* __restrict__ S1)
{
    __shared__ __attribute__((aligned(16))) u16 As[3][8192];   // 256r x 32k
    __shared__ __attribute__((aligned(16))) u16 Bs[3][4096];   // 128r x 32k
    __shared__ float part[4][128];

    const int tid = threadIdx.x, lane = tid & 63, w = tid >> 6;
    const int wh = w >> 1, wn = w & 1;
    const int bid = blockIdx.x;
    const int g8 = bid & 7, rest = bid >> 3;     // xcd-slice: 8 o x 32 nt per XCD
    const int o = g8 * 8 + (rest & 7);
    const int ntile = rest >> 3;                 // 0..31

    // staging decode: instr i covers rows 16i..16i+15; lane: row rl=lane>>2, phys slot p=lane&3
    // logical slot s = p ^ ((rl + rl>>2)&3)  (instr-index terms cancel mod 4)
    const int rl = lane >> 2;
    const int sw = ((lane & 3) ^ ((rl + (rl >> 2)) & 3)) << 3;   // u16 col offset
    const u16* aS0 = W0b + (o * 256 + (w * 2 + 0) * 16 + rl) * 256 + sw;
    const u16* aS1 = W0b + (o * 256 + (w * 2 + 1) * 16 + rl) * 256 + sw;
    const u16* bS0 = Qt + (ntile * 128 + w * 16 + rl) * 256 + sw;
    const int ldsA0 = (w * 2 + 0) * 512, ldsA1 = (w * 2 + 1) * 512;
    const int ldsB0 = w * 512;

    // frag read: row r = rb + 16f; slot sl=lane>>4 at phys sl^((r+r>>2)&3); f-term cancels mod 4
    const int rbA = wh * 64 + (lane & 15);
    const int rbB = wn * 64 + (lane & 15);
    const int sl = lane >> 4;
    const int aOff = rbA * 32 + ((sl ^ ((rbA + (rbA >> 2)) & 3)) << 3);
    const int bOff = rbB * 32 + ((sl ^ ((rbB + (rbB >> 2)) & 3)) << 3);

    f32x4 zero = {0.f, 0.f, 0.f, 0.f};
    f32x4 acc[4][4];
#pragma unroll
    for (int f = 0; f < 4; ++f)
#pragma unroll
        for (int gg = 0; gg < 4; ++gg) acc[f][gg] = zero;

    auto stage = [&](int kc, int bb) {
        int ko = kc * 32;
        gload_lds16(aS0 + ko, &As[bb][ldsA0]);
        gload_lds16(aS1 + ko, &As[bb][ldsA1]);
        gload_lds16(bS0 + ko, &Bs[bb][ldsB0]);
    };

    stage(0, 0); stage(1, 1);
#pragma unroll
    for (int kc = 0; kc < 8; ++kc) {
        if (kc < 7) asm volatile("s_waitcnt vmcnt(3)" ::: "memory");  // stage(kc) done, kc+1 in flight
        else        asm volatile("s_waitcnt vmcnt(0)" ::: "memory");
        __builtin_amdgcn_s_barrier();
        asm volatile("" ::: "memory");
        if (kc < 6) stage(kc + 2, (kc + 2) % 3);
        const u16* Ab = &As[kc % 3][0];
        const u16* Bb = &Bs[kc % 3][0];
        bf16x8 a[4], b[4];
#pragma unroll
        for (int f = 0; f < 4; ++f)
            a[f] = *reinterpret_cast<const bf16x8*>(Ab + aOff + f * 512);
#pragma unroll
        for (int gg = 0; gg < 4; ++gg)
            b[gg] = *reinterpret_cast<const bf16x8*>(Bb + bOff + gg * 512);
        __builtin_amdgcn_s_setprio(1);
#pragma unroll
        for (int f = 0; f < 4; ++f)
#pragma unroll
            for (int gg = 0; gg < 4; ++gg)
                acc[f][gg] = __builtin_amdgcn_mfma_f32_16x16x32_bf16(a[f], b[gg], acc[f][gg], 0, 0, 0);
        __builtin_amdgcn_s_setprio(0);
    }

    // epilogue: X1[o][n] = sum_h Q[h][n]*G[h][n]; E1 pre-packed per fragment
    float psum[4] = {0.f, 0.f, 0.f, 0.f};
    const u16* eb = E1 + ntile * 32768 + wh * 8192 + wn * 4096 + lane * 4;
#pragma unroll
    for (int f = 0; f < 4; ++f)
#pragma unroll
        for (int gg = 0; gg < 4; ++gg) {
            ushort4 wv = *reinterpret_cast<const ushort4*>(eb + f * 1024 + gg * 256);
            psum[gg] += bf2f(wv.x) * acc[f][gg][0] + bf2f(wv.y) * acc[f][gg][1]
                      + bf2f(wv.z) * acc[f][gg][2] + bf2f(wv.w) * acc[f][gg][3];
        }
#pragma unroll
    for (int gg = 0; gg < 4; ++gg) {
        float p = psum[gg];
        p += __shfl_xor(p, 16);
        p += __shfl_xor(p, 32);
        if (lane < 16) part[wh][wn * 64 + gg * 16 + lane] = p;
    }
    __syncthreads();
    if (tid < 128) {
        const int nl = tid;
        float v = part[0][nl] + part[1][nl] + part[2][nl] + part[3][nl] + b0[o];
        float r = fmaxf(v, 0.0f);
        const int n = ntile * 128 + nl;
        if (o < 32) {
            // E2 pack: [ntile 32][wn 2][g 4][c 16][h 32]
            E2[((ntile * 2 + (nl >> 6)) * 4 + ((nl >> 4) & 3)) * 512 + (nl & 15) * 32 + o] = f2bf(r);
        } else {
            float s = r;
            s += __shfl_xor(s, 1); s += __shfl_xor(s, 2);
            s += __shfl_xor(s, 4); s += __shfl_xor(s, 8);
            if ((nl & 15) == 0) S1[(n >> 4) * 32 + (o - 32)] = s;
        }
    }
}

// ---------------- stage 3: layer 2 ----------------
// 512 blocks x 256 thr. Tile 128r(4o x 32h) x 128n, BK=32, 3 bufs, depth-2.
// 4 waves of 64x64 (wh 0..1, wn 0..1). 3 blocks/CU resident.
__global__ __launch_bounds__(256, 4) void cin2_kernel(
    const u16* __restrict__ W1b, const u16* __restrict__ Qt, const u16* __restrict__ E2,
    const float* __restrict__ b1, float* __restrict__ S2)
{
    __shared__ __attribute__((aligned(16))) u16 As[3][4096];   // 128r x 32k
    __shared__ __attribute__((aligned(16))) u16 Bs[3][4096];
    __shared__ float part[2][2][128];

    const int tid = threadIdx.x, lane = tid & 63, w = tid >> 6;
    const int wh = w >> 1, wn = w & 1;
    const int bid = blockIdx.x;
    const int g8 = bid & 7, rest = bid >> 3;     // 0..63
    const int og = g8 * 2 + (rest & 1);          // 0..15
    const int ntile = rest >> 1;                 // 0..31

    const int rl = lane >> 2;
    const int sw = ((lane & 3) ^ ((rl + (rl >> 2)) & 3)) << 3;
    const u16* aS0 = W1b + (og * 128 + (w * 2 + 0) * 16 + rl) * 256 + sw;
    const u16* aS1 = W1b + (og * 128 + (w * 2 + 1) * 16 + rl) * 256 + sw;
    const u16* bS0 = Qt + (ntile * 128 + (w * 2 + 0) * 16 + rl) * 256 + sw;
    const u16* bS1 = Qt + (ntile * 128 + (w * 2 + 1) * 16 + rl) * 256 + sw;
    const int ldsI0 = (w * 2 + 0) * 512, ldsI1 = (w * 2 + 1) * 512;

    const int rbA = wh * 64 + (lane & 15);
    const int rbB = wn * 64 + (lane & 15);
    const int sl = lane >> 4;
    const int aOff = rbA * 32 + ((sl ^ ((rbA + (rbA >> 2)) & 3)) << 3);
    const int bOff = rbB * 32 + ((sl ^ ((rbB + (rbB >> 2)) & 3)) << 3);

    f32x4 zero = {0.f, 0.f, 0.f, 0.f};
    f32x4 acc[4][4];
#pragma unroll
    for (int f = 0; f < 4; ++f)
#pragma unroll
        for (int gg = 0; gg < 4; ++gg) acc[f][gg] = zero;

    auto stage = [&](int kc, int bb) {
        int ko = kc * 32;
        gload_lds16(aS0 + ko, &As[bb][ldsI0]);
        gload_lds16(aS1 + ko, &As[bb][ldsI1]);
        gload_lds16(bS0 + ko, &Bs[bb][ldsI0]);
        gload_lds16(bS1 + ko, &Bs[bb][ldsI1]);
    };

    stage(0, 0); stage(1, 1);
#pragma unroll
    for (int kc = 0; kc < 8; ++kc) {
        if (kc < 7) asm volatile("s_waitcnt vmcnt(4)" ::: "memory");
        else        asm volatile("s_waitcnt vmcnt(0)" ::: "memory");
        __builtin_amdgcn_s_barrier();
        asm volatile("" ::: "memory");
        if (kc < 6) stage(kc + 2, (kc + 2) % 3);
        const u16* Ab = &As[kc % 3][0];
        const u16* Bb = &Bs[kc % 3][0];
        bf16x8 a[4], b[4];
#pragma unroll
        for (int f = 0; f < 4; ++f)
            a[f] = *reinterpret_cast<const bf16x8*>(Ab + aOff + f * 512);
#pragma unroll
        for (int gg = 0; gg < 4; ++gg)
            b[gg] = *reinterpret_cast<const bf16x8*>(Bb + bOff + gg * 512);
        __builtin_amdgcn_s_setprio(1);
#pragma unroll
        for (int f = 0; f < 4; ++f)
#pragma unroll
            for (int gg = 0; gg < 4; ++gg)
                acc[f][gg] = __builtin_amdgcn_mfma_f32_16x16x32_bf16(a[f], b[gg], acc[f][gg], 0, 0, 0);
        __builtin_amdgcn_s_setprio(0);
    }

    // rows rt = wh*64 + f*16 + 4s + e; o_local = 2wh + (f>>1); h = (f&1)*16 + 4s + e
    float psum[2][4] = {{0.f,0.f,0.f,0.f},{0.f,0.f,0.f,0.f}};
    const u16* eb = E2 + (ntile * 2 + wn) * 2048 + (lane & 15) * 32 + (lane >> 4) * 4;
#pragma unroll
    for (int f = 0; f < 4; ++f)
#pragma unroll
        for (int gg = 0; gg < 4; ++gg) {
            ushort4 wv = *reinterpret_cast<const ushort4*>(eb + gg * 512 + (f & 1) * 16);
            psum[f >> 1][gg] += bf2f(wv.x) * acc[f][gg][0] + bf2f(wv.y) * acc[f][gg][1]
                              + bf2f(wv.z) * acc[f][gg][2] + bf2f(wv.w) * acc[f][gg][3];
        }
#pragma unroll
    for (int ol = 0; ol < 2; ++ol)
#pragma unroll
        for (int gg = 0; gg < 4; ++gg) {
            float p = psum[ol][gg];
            p += __shfl_xor(p, 16);
            p += __shfl_xor(p, 32);
            if (lane < 16) part[wh][ol][wn * 64 + gg * 16 + lane] = p;
        }
    __syncthreads();
    if (tid < 128) {
        const int nl = tid;
        const int n = ntile * 128 + nl;
#pragma unroll
        for (int o4 = 0; o4 < 4; ++o4) {
            const int oo = og * 4 + o4;
            float v = part[o4 >> 1][o4 & 1][nl] + b1[oo];
            float r = fmaxf(v, 0.0f);
            float s = r;
            s += __shfl_xor(s, 1); s += __shfl_xor(s, 2);
            s += __shfl_xor(s, 4); s += __shfl_xor(s, 8);
            if ((nl & 15) == 0) S2[(n >> 4) * 64 + oo] = s;
        }
    }
}

// ---------------- stage 4: final FC ----------------
__global__ void final_fc_kernel(const float* __restrict__ S1, const float* __restrict__ S2,
                                const float* __restrict__ fcW, const float* __restrict__ fcb,
                                float* __restrict__ out) {
    int b = threadIdx.x;   // 256
    float a0 = fcb[0], a1 = fcb[1];
#pragma unroll 8
    for (int c = 0; c < 32; ++c) {
        float v = S1[b * 32 + c];
        a0 += v * fcW[c]; a1 += v * fcW[96 + c];
    }
#pragma unroll 8
    for (int c = 0; c < 64; ++c) {
        float v = S2[b * 64 + c];
        a0 += v * fcW[32 + c]; a1 += v * fcW[96 + 32 + c];
    }
    out[b * 2 + 0] = a0;
    out[b * 2 + 1] = a1;
}

extern "C" void kernel_launch(void* const* d_in, const int* in_sizes, int n_in,
                              void* d_out, int out_size, void* d_ws, size_t ws_size,
                              hipStream_t stream) {
    const float* x   = (const float*)d_in[0];
    const float* emb = (const float*)d_in[1];
    const float* W0  = (const float*)d_in[2];
    const float* b0  = (const float*)d_in[3];
    const float* W1  = (const float*)d_in[4];
    const float* b1  = (const float*)d_in[5];
    const float* fcW = (const float*)d_in[6];
    const float* fcb = (const float*)d_in[7];
    float* out = (float*)d_out;

    char* ws = (char*)d_ws;
    u16*   W0b = (u16*)(ws);                 //  8,388,608 B
    u16*   W1b = (u16*)(ws + 8388608);       //  1,048,576 B
    u16*   Qt  = (u16*)(ws + 9437184);       //  2,097,152 B
    u16*   E1  = (u16*)(ws + 11534336);      //  2,097,152 B
    u16*   E2  = (u16*)(ws + 13631488);      //    262,144 B
    float* S1  = (float*)(ws + 13893632);    //     32,768 B
    float* S2  = (float*)(ws + 13926400);    //     65,536 B

    prep_kernel<<<5632, 256, 0, stream>>>(W0, W1, x, emb, W0b, W1b, Qt, E1);
    cin1_kernel<<<2048, 512, 0, stream>>>(W0b, Qt, E1, b0, E2, S1);
    cin2_kernel<<<512, 256, 0, stream>>>(W1b, Qt, E2, b1, S2);
    final_fc_kernel<<<1, 256, 0, stream>>>(S1, S2, fcW, fcb, out);
}